// Round 2
// baseline (1269.726 us; speedup 1.0000x reference)
//
#include <hip/hip_runtime.h>
#include <hip/hip_bf16.h>

typedef float f32x4 __attribute__((ext_vector_type(4)));
typedef __bf16 bf16x8 __attribute__((ext_vector_type(8)));
typedef __bf16 bf16x4 __attribute__((ext_vector_type(4)));

#define DEVI static __device__ __forceinline__

DEVI void glds16(const void* g, void* l) {
  __builtin_amdgcn_global_load_lds((__attribute__((address_space(1))) void*)g,
                                   (__attribute__((address_space(3))) void*)l, 16, 0, 0);
}

DEVI f32x4 load4(const float* p) { return *(const f32x4*)p; }
DEVI f32x4 load4(const __bf16* p) {
  bf16x4 v = *(const bf16x4*)p;
  f32x4 o = { (float)v[0], (float)v[1], (float)v[2], (float)v[3] };
  return o;
}
DEVI void store4(float* p, f32x4 v) { *(f32x4*)p = v; }
DEVI void store4(__bf16* p, f32x4 v) {
  bf16x4 o = { (__bf16)v[0], (__bf16)v[1], (__bf16)v[2], (__bf16)v[3] };
  *(bf16x4*)p = o;
}

// ---------------- weight fp32 -> bf16 ----------------
__global__ void cvt_bf16(const float* __restrict__ in, __bf16* __restrict__ out, int n4) {
  int i = blockIdx.x * 256 + threadIdx.x;
  if (i < n4) {
    f32x4 v = *(const f32x4*)(in + (size_t)i * 4);
    store4(out + (size_t)i * 4, v);
  }
}

// ---------------- LayerNorm over C=1024, one block per token ----------------
template <typename TIN, typename TOUT>
__global__ __launch_bounds__(256) void ln_kernel(const TIN* __restrict__ x,
    const float* __restrict__ gw, const float* __restrict__ bw,
    TOUT* __restrict__ out) {
  const size_t row = blockIdx.x;
  f32x4 v = load4(x + row * 1024 + threadIdx.x * 4);
  float s = v[0] + v[1] + v[2] + v[3];
  float q = v[0]*v[0] + v[1]*v[1] + v[2]*v[2] + v[3]*v[3];
#pragma unroll
  for (int o = 32; o > 0; o >>= 1) { s += __shfl_down(s, o); q += __shfl_down(q, o); }
  __shared__ float ss[4], qq[4];
  const int w = threadIdx.x >> 6, l = threadIdx.x & 63;
  if (l == 0) { ss[w] = s; qq[w] = q; }
  __syncthreads();
  s = ss[0] + ss[1] + ss[2] + ss[3];
  q = qq[0] + qq[1] + qq[2] + qq[3];
  const float mean = s * (1.0f / 1024.0f);
  const float var = q * (1.0f / 1024.0f) - mean * mean;
  const float rstd = rsqrtf(var + 1e-5f);
  f32x4 g4 = *(const f32x4*)(gw + threadIdx.x * 4);
  f32x4 b4 = *(const f32x4*)(bw + threadIdx.x * 4);
  f32x4 o;
#pragma unroll
  for (int j = 0; j < 4; ++j) o[j] = (v[j] - mean) * rstd * g4[j] + b4[j];
  store4(out + row * 1024 + threadIdx.x * 4, o);
}

// ---------------- time-shift mix -> bf16 ----------------
// xm = x*tm + x[t-1]*(1-tm) + (c<512 ? x[t-1] : x[t+1])*cm
template <typename TIN>
__global__ __launch_bounds__(256) void mix_kernel(const TIN* __restrict__ x,
    const float* __restrict__ tm, const float* __restrict__ cm,
    __bf16* __restrict__ out) {
  const int idx = blockIdx.x * 256 + threadIdx.x;   // over B*T*C/4
  const int t = (idx >> 8) & 2047;                   // T=2048
  const int c = (idx & 255) * 4;                     // C/4=256
  const size_t base = ((size_t)(idx >> 8) << 10) + c;  // (b*T+t)*C + c
  f32x4 xv = load4(x + base);
  f32x4 xm1 = {0.f, 0.f, 0.f, 0.f}, xp1 = {0.f, 0.f, 0.f, 0.f};
  if (t > 0)    xm1 = load4(x + base - 1024);
  if (t < 2047) xp1 = load4(x + base + 1024);
  f32x4 tm4 = *(const f32x4*)(tm + c);
  f32x4 cm4 = *(const f32x4*)(cm + c);
  f32x4 xc = (c < 512) ? xm1 : xp1;
  f32x4 o;
#pragma unroll
  for (int j = 0; j < 4; ++j)
    o[j] = xv[j] * tm4[j] + xm1[j] * (1.0f - tm4[j]) + xc[j] * cm4[j];
  store4(out + base, o);
}

// ---------------- WKV scan: one thread per (b,c), serial over T ----------------
// y_t = (a + eu*k*v)/(b + eu*k);  a = ed*a + k*v;  b = ed*b + k
// writes srw = sigmoid_r * y as bf16 (input to Wo GEMM). All state fp32.
__global__ __launch_bounds__(64) void wkv_kernel(const __bf16* __restrict__ k,
    const __bf16* __restrict__ v, const __bf16* __restrict__ sr,
    const float* __restrict__ td, const float* __restrict__ tf,
    __bf16* __restrict__ srw) {
  const int gid = blockIdx.x * 64 + threadIdx.x;   // 8192 threads
  const int c = gid & 1023;
  const int bb = gid >> 10;
  const float ed = expf(-expf(td[c]));
  const float eu = expf(tf[c]);
  float aa = 0.f, bbv = 0.f;
  size_t off = (size_t)bb * 2048 * 1024 + c;
#pragma unroll 8
  for (int t = 0; t < 2048; ++t, off += 1024) {
    const float kt = (float)k[off];
    const float vt = (float)v[off];
    const float kv = kt * vt;
    const float y = (aa + eu * kv) / (bbv + eu * kt);
    srw[off] = (__bf16)((float)sr[off] * y);
    aa = ed * aa + kv;
    bbv = ed * bbv + kt;
  }
}

// ---------------- bf16 MFMA GEMM: out[m,n] = sum_k A[m,k]*W[n,k] ----------------
// 128x128 tile, BK=32, 4 waves (2x2), 16x16x32 MFMA, global_load_lds staging.
enum { EPI_NONE = 0, EPI_EXP, EPI_SIG, EPI_RELU2, EPI_RESID, EPI_FINAL };

template <int EPI>
__global__ __launch_bounds__(256) void gemm_bt(
    const __bf16* __restrict__ A, const __bf16* __restrict__ W,
    void* outp, const void* res, const void* sig, const int N, const int K) {
  __shared__ __bf16 sA[128 * 32];
  __shared__ __bf16 sB[128 * 32];
  const int tid = threadIdx.x;
  const int w = tid >> 6, l = tid & 63;
  const int m0 = blockIdx.y << 7, n0 = blockIdx.x << 7;
  const int wr = (w >> 1) << 6;  // wave row offset 0/64
  const int wc = (w & 1) << 6;   // wave col offset 0/64

  f32x4 acc[4][4] = {};

  const int r0 = tid >> 2, cc0 = (tid & 3) << 3;
  const __bf16* gA0 = A + (size_t)(m0 + r0) * K + cc0;
  const __bf16* gA1 = A + (size_t)(m0 + r0 + 64) * K + cc0;
  const __bf16* gB0 = W + (size_t)(n0 + r0) * K + cc0;
  const __bf16* gB1 = W + (size_t)(n0 + r0 + 64) * K + cc0;
  __bf16* lA0 = sA + w * 512;         // wave-uniform LDS base (+lane*16B in HW)
  __bf16* lA1 = sA + 2048 + w * 512;
  __bf16* lB0 = sB + w * 512;
  __bf16* lB1 = sB + 2048 + w * 512;

  const __bf16* pa = sA + ((wr + (l & 15)) << 5) + ((l >> 4) << 3);
  const __bf16* pb = sB + ((wc + (l & 15)) << 5) + ((l >> 4) << 3);

  for (int kk = 0; kk < K; kk += 32) {
    glds16(gA0 + kk, lA0);
    glds16(gA1 + kk, lA1);
    glds16(gB0 + kk, lB0);
    glds16(gB1 + kk, lB1);
    __syncthreads();
    bf16x8 af[4], bfv[4];
#pragma unroll
    for (int i = 0; i < 4; ++i) {
      af[i]  = *(const bf16x8*)(pa + (i << 9));   // +i*16 rows * 32
      bfv[i] = *(const bf16x8*)(pb + (i << 9));
    }
#pragma unroll
    for (int mi = 0; mi < 4; ++mi)
#pragma unroll
      for (int ni = 0; ni < 4; ++ni)
        acc[mi][ni] = __builtin_amdgcn_mfma_f32_16x16x32_bf16(af[mi], bfv[ni], acc[mi][ni], 0, 0, 0);
    __syncthreads();
  }

  // epilogue: C/D map col=lane&15, row=(lane>>4)*4+reg
  const int rl = (l >> 4) << 2, cl = l & 15;
#pragma unroll
  for (int mi = 0; mi < 4; ++mi) {
#pragma unroll
    for (int ni = 0; ni < 4; ++ni) {
#pragma unroll
      for (int e = 0; e < 4; ++e) {
        const int r = m0 + wr + mi * 16 + rl + e;
        const int cidx = n0 + wc + ni * 16 + cl;
        const size_t idx = (size_t)r * N + cidx;
        const float vacc = acc[mi][ni][e];
        if constexpr (EPI == EPI_NONE) {
          ((__bf16*)outp)[idx] = (__bf16)vacc;
        } else if constexpr (EPI == EPI_EXP) {
          ((__bf16*)outp)[idx] = (__bf16)expf(fminf(vacc, 60.0f));
        } else if constexpr (EPI == EPI_SIG) {
          ((__bf16*)outp)[idx] = (__bf16)(1.0f / (1.0f + expf(-vacc)));
        } else if constexpr (EPI == EPI_RELU2) {
          const float rv = fmaxf(vacc, 0.0f);
          ((__bf16*)outp)[idx] = (__bf16)(rv * rv);
        } else if constexpr (EPI == EPI_RESID) {
          // in-place: outp == res (same idx read-then-write, race-free)
          ((__bf16*)outp)[idx] = (__bf16)(vacc + (float)((const __bf16*)res)[idx]);
        } else {  // EPI_FINAL: out(f32) = res(f32, in-place) + sig(bf16)*acc
          ((float*)outp)[idx] = ((const float*)res)[idx] + (float)((const __bf16*)sig)[idx] * vacc;
        }
      }
    }
  }
}

// ---------------- launch ----------------
extern "C" void kernel_launch(void* const* d_in, const int* in_sizes, int n_in,
                              void* d_out, int out_size, void* d_ws, size_t ws_size,
                              hipStream_t stream) {
  (void)in_sizes; (void)n_in; (void)out_size; (void)ws_size;
  const float* x    = (const float*)d_in[0];
  const float* ln1g = (const float*)d_in[1];
  const float* ln1b = (const float*)d_in[2];
  const float* ln2g = (const float*)d_in[3];
  const float* ln2b = (const float*)d_in[4];
  const float* atm  = (const float*)d_in[5];
  const float* acm  = (const float*)d_in[6];
  const float* td   = (const float*)d_in[7];
  const float* tf   = (const float*)d_in[8];
  const float* Wk   = (const float*)d_in[9];
  const float* Wv   = (const float*)d_in[10];
  const float* Wr   = (const float*)d_in[11];
  const float* Wo   = (const float*)d_in[12];
  const float* ftm  = (const float*)d_in[13];
  const float* fcm  = (const float*)d_in[14];
  const float* Fk   = (const float*)d_in[15];
  const float* Fv   = (const float*)d_in[16];
  const float* Fr   = (const float*)d_in[17];

  constexpr size_t C = 1024, T = 2048, Bs = 8, H = 4096;
  constexpr size_t NT = Bs * T;        // 16384 tokens
  constexpr size_t NTC = NT * C;       // 16M elems
  constexpr size_t CC = C * C;
  constexpr size_t CH = C * H;

  // ---- workspace: 26 MiB weights + 4 x 32 MiB bf16 activations = 154 MiB ----
  char* p = (char*)d_ws;
  auto takeb = [&](size_t elems) { __bf16* q = (__bf16*)p; p += elems * 2; return q; };
  __bf16* wWk = takeb(CC);
  __bf16* wWv = takeb(CC);
  __bf16* wWr = takeb(CC);
  __bf16* wWo = takeb(CC);
  __bf16* wFk = takeb(CH);
  __bf16* wFv = takeb(CH);
  __bf16* wFr = takeb(CC);
  __bf16* Ab  = takeb(NTC);   // x1 -> x2 (in-place residual)
  __bf16* Bb  = takeb(NTC);   // xm -> srw -> sr2
  __bf16* Cb  = takeb(NTC);   // k  -> kk chunk (4096x4096 bf16 = 32 MiB)
  __bf16* Db  = takeb(NTC);   // v  -> xm2
  __bf16* sr  = (__bf16*)d_out;   // sigmoid(r) borrows d_out until ln2 overwrites it
  float*  x3  = (float*)d_out;    // ln2 output lives in d_out (final GEMM is in-place)

  auto cvt = [&](const float* src, size_t n, __bf16* dst) {
    const int n4 = (int)(n / 4);
    cvt_bf16<<<dim3((n4 + 255) / 256), dim3(256), 0, stream>>>(src, dst, n4);
  };
  cvt(Wk, CC, wWk); cvt(Wv, CC, wWv); cvt(Wr, CC, wWr); cvt(Wo, CC, wWo);
  cvt(Fk, CH, wFk); cvt(Fv, CH, wFv); cvt(Fr, CC, wFr);

  const dim3 blk(256);
  const dim3 g8(8, 128);    // 16384 x 1024

  // x1 = ln1(x)            [Ab]
  ln_kernel<float, __bf16><<<dim3((unsigned)NT), blk, 0, stream>>>(x, ln1g, ln1b, Ab);
  // xm = mix(x1)           [Bb]
  mix_kernel<__bf16><<<dim3((unsigned)(NTC / 1024)), blk, 0, stream>>>(Ab, atm, acm, Bb);
  // k, v, sigmoid(r)
  gemm_bt<EPI_EXP><<<g8, blk, 0, stream>>>(Bb, wWk, Cb, nullptr, nullptr, 1024, 1024);
  gemm_bt<EPI_NONE><<<g8, blk, 0, stream>>>(Bb, wWv, Db, nullptr, nullptr, 1024, 1024);
  gemm_bt<EPI_SIG><<<g8, blk, 0, stream>>>(Bb, wWr, sr, nullptr, nullptr, 1024, 1024);
  // srw = sigmoid(r) * wkv(k,v)   [Bb; xm dead]
  wkv_kernel<<<dim3(128), dim3(64), 0, stream>>>(Cb, Db, sr, td, tf, Bb);
  // x2 = x1 + srw@Wo^T     [Ab in-place]
  gemm_bt<EPI_RESID><<<g8, blk, 0, stream>>>(Bb, wWo, Ab, Ab, nullptr, 1024, 1024);
  // x3 = ln2(x2)           [d_out, fp32]
  ln_kernel<__bf16, float><<<dim3((unsigned)NT), blk, 0, stream>>>(Ab, ln2g, ln2b, x3);
  // xm2 = mix(x3)          [Db; v dead]
  mix_kernel<float><<<dim3((unsigned)(NTC / 1024)), blk, 0, stream>>>(x3, ftm, fcm, Db);
  // sr2 = sigmoid(xm2@Fr^T) [Bb; srw dead]
  gemm_bt<EPI_SIG><<<g8, blk, 0, stream>>>(Db, wFr, Bb, nullptr, nullptr, 1024, 1024);
  // FFN chunked over 4 x 4096 tokens: kk = relu(xm2@Fk^T)^2 [Cb], out += sr2 * kk@Fv^T
  for (int ch = 0; ch < 4; ++ch) {
    const size_t ro = (size_t)ch * 4096;
    gemm_bt<EPI_RELU2><<<dim3(32, 32), blk, 0, stream>>>(
        Db + ro * 1024, wFk, Cb, nullptr, nullptr, 4096, 1024);
    gemm_bt<EPI_FINAL><<<dim3(8, 32), blk, 0, stream>>>(
        Cb, wFv, (float*)d_out + ro * 1024, (const float*)d_out + ro * 1024,
        Bb + ro * 1024, 1024, 4096);
  }
}

// Round 3
// 1086.158 us; speedup vs baseline: 1.1690x; 1.1690x over previous
//
#include <hip/hip_runtime.h>
#include <hip/hip_bf16.h>

typedef float f32x4 __attribute__((ext_vector_type(4)));
typedef __bf16 bf16x8 __attribute__((ext_vector_type(8)));
typedef __bf16 bf16x4 __attribute__((ext_vector_type(4)));

#define DEVI static __device__ __forceinline__

DEVI void glds16(const void* g, void* l) {
  __builtin_amdgcn_global_load_lds((__attribute__((address_space(1))) void*)g,
                                   (__attribute__((address_space(3))) void*)l, 16, 0, 0);
}

DEVI f32x4 load4(const float* p) { return *(const f32x4*)p; }
DEVI f32x4 load4(const __bf16* p) {
  bf16x4 v = *(const bf16x4*)p;
  f32x4 o = { (float)v[0], (float)v[1], (float)v[2], (float)v[3] };
  return o;
}
DEVI void store4(float* p, f32x4 v) { *(f32x4*)p = v; }
DEVI void store4(__bf16* p, f32x4 v) {
  bf16x4 o = { (__bf16)v[0], (__bf16)v[1], (__bf16)v[2], (__bf16)v[3] };
  *(bf16x4*)p = o;
}

// ---------------- weight fp32 -> bf16 ----------------
__global__ void cvt_bf16(const float* __restrict__ in, __bf16* __restrict__ out, int n4) {
  int i = blockIdx.x * 256 + threadIdx.x;
  if (i < n4) {
    f32x4 v = *(const f32x4*)(in + (size_t)i * 4);
    store4(out + (size_t)i * 4, v);
  }
}

// ---------------- LayerNorm over C=1024, one block per token ----------------
template <typename TIN, typename TOUT>
__global__ __launch_bounds__(256) void ln_kernel(const TIN* __restrict__ x,
    const float* __restrict__ gw, const float* __restrict__ bw,
    TOUT* __restrict__ out) {
  const size_t row = blockIdx.x;
  f32x4 v = load4(x + row * 1024 + threadIdx.x * 4);
  float s = v[0] + v[1] + v[2] + v[3];
  float q = v[0]*v[0] + v[1]*v[1] + v[2]*v[2] + v[3]*v[3];
#pragma unroll
  for (int o = 32; o > 0; o >>= 1) { s += __shfl_down(s, o); q += __shfl_down(q, o); }
  __shared__ float ss[4], qq[4];
  const int w = threadIdx.x >> 6, l = threadIdx.x & 63;
  if (l == 0) { ss[w] = s; qq[w] = q; }
  __syncthreads();
  s = ss[0] + ss[1] + ss[2] + ss[3];
  q = qq[0] + qq[1] + qq[2] + qq[3];
  const float mean = s * (1.0f / 1024.0f);
  const float var = q * (1.0f / 1024.0f) - mean * mean;
  const float rstd = rsqrtf(var + 1e-5f);
  f32x4 g4 = *(const f32x4*)(gw + threadIdx.x * 4);
  f32x4 b4 = *(const f32x4*)(bw + threadIdx.x * 4);
  f32x4 o;
#pragma unroll
  for (int j = 0; j < 4; ++j) o[j] = (v[j] - mean) * rstd * g4[j] + b4[j];
  store4(out + row * 1024 + threadIdx.x * 4, o);
}

// ---------------- time-shift mix -> bf16 ----------------
template <typename TIN>
__global__ __launch_bounds__(256) void mix_kernel(const TIN* __restrict__ x,
    const float* __restrict__ tm, const float* __restrict__ cm,
    __bf16* __restrict__ out) {
  const int idx = blockIdx.x * 256 + threadIdx.x;   // over B*T*C/4
  const int t = (idx >> 8) & 2047;                   // T=2048
  const int c = (idx & 255) * 4;                     // C/4=256
  const size_t base = ((size_t)(idx >> 8) << 10) + c;
  f32x4 xv = load4(x + base);
  f32x4 xm1 = {0.f, 0.f, 0.f, 0.f}, xp1 = {0.f, 0.f, 0.f, 0.f};
  if (t > 0)    xm1 = load4(x + base - 1024);
  if (t < 2047) xp1 = load4(x + base + 1024);
  f32x4 tm4 = *(const f32x4*)(tm + c);
  f32x4 cm4 = *(const f32x4*)(cm + c);
  f32x4 xc = (c < 512) ? xm1 : xp1;
  f32x4 o;
#pragma unroll
  for (int j = 0; j < 4; ++j)
    o[j] = xv[j] * tm4[j] + xm1[j] * (1.0f - tm4[j]) + xc[j] * cm4[j];
  store4(out + base, o);
}

// ---------------- WKV chunk-parallel scan ----------------
// T=2048 split into 32 chunks of L=64. Linear recurrence a=ed*a+kv decomposes:
// pass1 computes chunk-local partials; scan combines carries (ed^64 step);
// pass2 re-walks chunks with carried-in state. Exact regroup of reference math.
__global__ __launch_bounds__(256) void wkv_part(const __bf16* __restrict__ k,
    const __bf16* __restrict__ v, const float* __restrict__ td,
    float* __restrict__ scA, float* __restrict__ scB) {
  const int gid = blockIdx.x * 256 + threadIdx.x;   // b*32768 + j*1024 + c
  const int c = gid & 1023;
  const int j = (gid >> 10) & 31;
  const int b = gid >> 15;
  const float ed = expf(-expf(td[c]));
  float A = 0.f, Bv = 0.f;
  size_t off = ((size_t)(b * 2048 + j * 64) << 10) + c;
#pragma unroll 4
  for (int i = 0; i < 64; ++i, off += 1024) {
    const float kt = (float)k[off];
    const float kv = kt * (float)v[off];
    A = ed * A + kv;
    Bv = ed * Bv + kt;
  }
  scA[gid] = A;
  scB[gid] = Bv;
}

__global__ __launch_bounds__(256) void wkv_scan(const float* __restrict__ td,
    float* __restrict__ scA, float* __restrict__ scB) {
  const int gid = blockIdx.x * 256 + threadIdx.x;   // 8192 = b*1024 + c
  const int c = gid & 1023;
  const int b = gid >> 10;
  const float edL = expf(-expf(td[c]) * 64.0f);     // ed^64
  float a = 0.f, bb = 0.f;
  size_t off = ((size_t)b << 15) + c;
  for (int j = 0; j < 32; ++j, off += 1024) {
    const float Aj = scA[off], Bj = scB[off];
    scA[off] = a;            // carry INTO chunk j
    scB[off] = bb;
    a = edL * a + Aj;
    bb = edL * bb + Bj;
  }
}

__global__ __launch_bounds__(256) void wkv_apply(const __bf16* __restrict__ k,
    const __bf16* __restrict__ v, const __bf16* __restrict__ sr,
    const float* __restrict__ td, const float* __restrict__ tf,
    const float* __restrict__ scA, const float* __restrict__ scB,
    __bf16* __restrict__ srw) {
  const int gid = blockIdx.x * 256 + threadIdx.x;
  const int c = gid & 1023;
  const int j = (gid >> 10) & 31;
  const int b = gid >> 15;
  const float ed = expf(-expf(td[c]));
  const float eu = expf(tf[c]);
  float a = scA[gid], bb = scB[gid];
  size_t off = ((size_t)(b * 2048 + j * 64) << 10) + c;
#pragma unroll 4
  for (int i = 0; i < 64; ++i, off += 1024) {
    const float kt = (float)k[off];
    const float vt = (float)v[off];
    const float kv = kt * vt;
    const float y = (a + eu * kv) / (bb + eu * kt);
    srw[off] = (__bf16)((float)sr[off] * y);
    a = ed * a + kv;
    bb = ed * bb + kt;
  }
}

// ---------------- bf16 MFMA GEMM: out[m,n] = sum_k A[m,k]*W[n,k] ----------------
// 128x128 tile, BK=32, 4 waves (2x2), 16x16x32 MFMA, global_load_lds staging,
// bijective XCD-aware block swizzle (all grids are %8==0).
enum { EPI_NONE = 0, EPI_EXP, EPI_SIG, EPI_RELU2, EPI_RESID, EPI_FINAL, EPI_KVR };

template <int EPI>
__global__ __launch_bounds__(256) void gemm_bt(
    const __bf16* __restrict__ A, const __bf16* __restrict__ W,
    void* outp, const void* res, const void* sig, const int N, const int K) {
  __shared__ __bf16 sA[128 * 32];
  __shared__ __bf16 sB[128 * 32];
  const int tid = threadIdx.x;
  const int w = tid >> 6, l = tid & 63;

  // XCD swizzle: contiguous chunk of tiles per XCD (nwg % 8 == 0 for all grids)
  const int nwg = gridDim.x * gridDim.y;
  int wg = blockIdx.y * gridDim.x + blockIdx.x;
  wg = (wg & 7) * (nwg >> 3) + (wg >> 3);
  const int m0 = (wg / gridDim.x) << 7;
  const int n0 = (wg % gridDim.x) << 7;

  const int wr = (w >> 1) << 6;
  const int wc = (w & 1) << 6;

  f32x4 acc[4][4] = {};

  const int r0 = tid >> 2, cc0 = (tid & 3) << 3;
  const __bf16* gA0 = A + (size_t)(m0 + r0) * K + cc0;
  const __bf16* gA1 = A + (size_t)(m0 + r0 + 64) * K + cc0;
  const __bf16* gB0 = W + (size_t)(n0 + r0) * K + cc0;
  const __bf16* gB1 = W + (size_t)(n0 + r0 + 64) * K + cc0;
  __bf16* lA0 = sA + w * 512;
  __bf16* lA1 = sA + 2048 + w * 512;
  __bf16* lB0 = sB + w * 512;
  __bf16* lB1 = sB + 2048 + w * 512;

  const __bf16* pa = sA + ((wr + (l & 15)) << 5) + ((l >> 4) << 3);
  const __bf16* pb = sB + ((wc + (l & 15)) << 5) + ((l >> 4) << 3);

  for (int kk = 0; kk < K; kk += 32) {
    glds16(gA0 + kk, lA0);
    glds16(gA1 + kk, lA1);
    glds16(gB0 + kk, lB0);
    glds16(gB1 + kk, lB1);
    __syncthreads();
    bf16x8 af[4], bfv[4];
#pragma unroll
    for (int i = 0; i < 4; ++i) {
      af[i]  = *(const bf16x8*)(pa + (i << 9));
      bfv[i] = *(const bf16x8*)(pb + (i << 9));
    }
#pragma unroll
    for (int mi = 0; mi < 4; ++mi)
#pragma unroll
      for (int ni = 0; ni < 4; ++ni)
        acc[mi][ni] = __builtin_amdgcn_mfma_f32_16x16x32_bf16(af[mi], bfv[ni], acc[mi][ni], 0, 0, 0);
    __syncthreads();
  }

  // epilogue: C/D map col=lane&15, row=(lane>>4)*4+reg
  const int rl = (l >> 4) << 2, cl = l & 15;
#pragma unroll
  for (int mi = 0; mi < 4; ++mi) {
#pragma unroll
    for (int ni = 0; ni < 4; ++ni) {
#pragma unroll
      for (int e = 0; e < 4; ++e) {
        const int r = m0 + wr + mi * 16 + rl + e;
        const int cidx = n0 + wc + ni * 16 + cl;
        const size_t idx = (size_t)r * N + cidx;
        const float vacc = acc[mi][ni][e];
        if constexpr (EPI == EPI_NONE) {
          ((__bf16*)outp)[idx] = (__bf16)vacc;
        } else if constexpr (EPI == EPI_EXP) {
          ((__bf16*)outp)[idx] = (__bf16)expf(fminf(vacc, 60.0f));
        } else if constexpr (EPI == EPI_SIG) {
          ((__bf16*)outp)[idx] = (__bf16)(1.0f / (1.0f + expf(-vacc)));
        } else if constexpr (EPI == EPI_RELU2) {
          const float rv = fmaxf(vacc, 0.0f);
          ((__bf16*)outp)[idx] = (__bf16)(rv * rv);
        } else if constexpr (EPI == EPI_RESID) {
          ((__bf16*)outp)[idx] = (__bf16)(vacc + (float)((const __bf16*)res)[idx]);
        } else if constexpr (EPI == EPI_FINAL) {
          ((float*)outp)[idx] = ((const float*)res)[idx] + (float)((const __bf16*)sig)[idx] * vacc;
        } else {  // EPI_KVR: n<1024 -> k=exp(clamp), <2048 -> v, else sigmoid(r)
          const int sel = cidx >> 10;
          const size_t oidx = (size_t)r * 1024 + (cidx & 1023);
          if (sel == 0)      ((__bf16*)outp)[oidx] = (__bf16)expf(fminf(vacc, 60.0f));
          else if (sel == 1) ((__bf16*)const_cast<void*>(res))[oidx] = (__bf16)vacc;
          else               ((__bf16*)const_cast<void*>(sig))[oidx] = (__bf16)(1.0f / (1.0f + expf(-vacc)));
        }
      }
    }
  }
}

// ---------------- launch ----------------
extern "C" void kernel_launch(void* const* d_in, const int* in_sizes, int n_in,
                              void* d_out, int out_size, void* d_ws, size_t ws_size,
                              hipStream_t stream) {
  (void)in_sizes; (void)n_in; (void)out_size; (void)ws_size;
  const float* x    = (const float*)d_in[0];
  const float* ln1g = (const float*)d_in[1];
  const float* ln1b = (const float*)d_in[2];
  const float* ln2g = (const float*)d_in[3];
  const float* ln2b = (const float*)d_in[4];
  const float* atm  = (const float*)d_in[5];
  const float* acm  = (const float*)d_in[6];
  const float* td   = (const float*)d_in[7];
  const float* tf   = (const float*)d_in[8];
  const float* Wk   = (const float*)d_in[9];
  const float* Wv   = (const float*)d_in[10];
  const float* Wr   = (const float*)d_in[11];
  const float* Wo   = (const float*)d_in[12];
  const float* ftm  = (const float*)d_in[13];
  const float* fcm  = (const float*)d_in[14];
  const float* Fk   = (const float*)d_in[15];
  const float* Fv   = (const float*)d_in[16];
  const float* Fr   = (const float*)d_in[17];

  constexpr size_t C = 1024, T = 2048, Bs = 8, H = 4096;
  constexpr size_t NT = Bs * T;        // 16384 tokens
  constexpr size_t NTC = NT * C;       // 16M elems
  constexpr size_t CC = C * C;
  constexpr size_t CH = C * H;

  // ---- workspace: 26 MiB weights + 128 MiB activations + 2 MiB wkv carries ----
  char* p = (char*)d_ws;
  auto takeb = [&](size_t elems) { __bf16* q = (__bf16*)p; p += elems * 2; return q; };
  __bf16* wKVR = takeb(3 * CC);   // [Wk; Wv; Wr] rows stacked -> (3072, 1024)
  __bf16* wWo  = takeb(CC);
  __bf16* wFk  = takeb(CH);
  __bf16* wFv  = takeb(CH);
  __bf16* wFr  = takeb(CC);
  __bf16* Ab   = takeb(NTC);   // x1 -> x2 (in-place residual)
  __bf16* Bb   = takeb(NTC);   // xm -> srw -> sr2
  __bf16* Cb   = takeb(NTC);   // k  -> kk chunk (4096x4096 bf16)
  __bf16* Db   = takeb(NTC);   // v  -> xm2
  float* scA = (float*)p; p += Bs * 32 * C * 4;   // wkv carries (b,j,c)
  float* scB = (float*)p; p += Bs * 32 * C * 4;
  __bf16* sr  = (__bf16*)d_out;   // sigmoid(r) borrows d_out until ln2 overwrites it
  float*  x3  = (float*)d_out;

  auto cvt = [&](const float* src, size_t n, __bf16* dst) {
    const int n4 = (int)(n / 4);
    cvt_bf16<<<dim3((n4 + 255) / 256), dim3(256), 0, stream>>>(src, dst, n4);
  };
  cvt(Wk, CC, wKVR); cvt(Wv, CC, wKVR + CC); cvt(Wr, CC, wKVR + 2 * CC);
  cvt(Wo, CC, wWo); cvt(Fk, CH, wFk); cvt(Fv, CH, wFv); cvt(Fr, CC, wFr);

  const dim3 blk(256);
  const dim3 g8(8, 128);    // 16384 x 1024

  // x1 = ln1(x)            [Ab]
  ln_kernel<float, __bf16><<<dim3((unsigned)NT), blk, 0, stream>>>(x, ln1g, ln1b, Ab);
  // xm = mix(x1)           [Bb]
  mix_kernel<__bf16><<<dim3((unsigned)(NTC / 1024)), blk, 0, stream>>>(Ab, atm, acm, Bb);
  // fused: k=exp(min(.,60)) [Cb], v [Db], sigmoid(r) [sr]
  gemm_bt<EPI_KVR><<<dim3(24, 128), blk, 0, stream>>>(Bb, wKVR, Cb, Db, sr, 3072, 1024);
  // wkv: chunk partials -> carry scan -> apply (srw = sigmoid(r)*y into Bb)
  wkv_part<<<dim3(1024), blk, 0, stream>>>(Cb, Db, td, scA, scB);
  wkv_scan<<<dim3(32), blk, 0, stream>>>(td, scA, scB);
  wkv_apply<<<dim3(1024), blk, 0, stream>>>(Cb, Db, sr, td, tf, scA, scB, Bb);
  // x2 = x1 + srw@Wo^T     [Ab in-place]
  gemm_bt<EPI_RESID><<<g8, blk, 0, stream>>>(Bb, wWo, Ab, Ab, nullptr, 1024, 1024);
  // x3 = ln2(x2)           [d_out, fp32]
  ln_kernel<__bf16, float><<<dim3((unsigned)NT), blk, 0, stream>>>(Ab, ln2g, ln2b, x3);
  // xm2 = mix(x3)          [Db]
  mix_kernel<float><<<dim3((unsigned)(NTC / 1024)), blk, 0, stream>>>(x3, ftm, fcm, Db);
  // sr2 = sigmoid(xm2@Fr^T) [Bb]
  gemm_bt<EPI_SIG><<<g8, blk, 0, stream>>>(Db, wFr, Bb, nullptr, nullptr, 1024, 1024);
  // FFN chunked over 4 x 4096 tokens: kk = relu(xm2@Fk^T)^2 [Cb], out += sr2 * kk@Fv^T
  for (int ch = 0; ch < 4; ++ch) {
    const size_t ro = (size_t)ch * 4096;
    gemm_bt<EPI_RELU2><<<dim3(32, 32), blk, 0, stream>>>(
        Db + ro * 1024, wFk, Cb, nullptr, nullptr, 4096, 1024);
    gemm_bt<EPI_FINAL><<<dim3(8, 32), blk, 0, stream>>>(
        Cb, wFv, (float*)d_out + ro * 1024, (const float*)d_out + ro * 1024,
        Bb + ro * 1024, 1024, 4096);
  }
}

// Round 4
// 783.332 us; speedup vs baseline: 1.6209x; 1.3866x over previous
//
#include <hip/hip_runtime.h>
#include <hip/hip_bf16.h>

typedef float f32x4 __attribute__((ext_vector_type(4)));
typedef __bf16 bf16x8 __attribute__((ext_vector_type(8)));
typedef __bf16 bf16x4 __attribute__((ext_vector_type(4)));

#define DEVI static __device__ __forceinline__

DEVI void glds16(const void* g, void* l) {
  __builtin_amdgcn_global_load_lds((__attribute__((address_space(1))) void*)g,
                                   (__attribute__((address_space(3))) void*)l, 16, 0, 0);
}

DEVI f32x4 load4(const float* p) { return *(const f32x4*)p; }
DEVI f32x4 load4(const __bf16* p) {
  bf16x4 v = *(const bf16x4*)p;
  f32x4 o = { (float)v[0], (float)v[1], (float)v[2], (float)v[3] };
  return o;
}
DEVI void store4(float* p, f32x4 v) { *(f32x4*)p = v; }
DEVI void store4(__bf16* p, f32x4 v) {
  bf16x4 o = { (__bf16)v[0], (__bf16)v[1], (__bf16)v[2], (__bf16)v[3] };
  *(bf16x4*)p = o;
}

// ---------------- weight fp32 -> bf16 ----------------
__global__ void cvt_bf16(const float* __restrict__ in, __bf16* __restrict__ out, int n4) {
  int i = blockIdx.x * 256 + threadIdx.x;
  if (i < n4) {
    f32x4 v = *(const f32x4*)(in + (size_t)i * 4);
    store4(out + (size_t)i * 4, v);
  }
}

// ---------------- LayerNorm over C=1024, one block per token ----------------
template <typename TIN, typename TOUT>
__global__ __launch_bounds__(256) void ln_kernel(const TIN* __restrict__ x,
    const float* __restrict__ gw, const float* __restrict__ bw,
    TOUT* __restrict__ out) {
  const size_t row = blockIdx.x;
  f32x4 v = load4(x + row * 1024 + threadIdx.x * 4);
  float s = v[0] + v[1] + v[2] + v[3];
  float q = v[0]*v[0] + v[1]*v[1] + v[2]*v[2] + v[3]*v[3];
#pragma unroll
  for (int o = 32; o > 0; o >>= 1) { s += __shfl_down(s, o); q += __shfl_down(q, o); }
  __shared__ float ss[4], qq[4];
  const int w = threadIdx.x >> 6, l = threadIdx.x & 63;
  if (l == 0) { ss[w] = s; qq[w] = q; }
  __syncthreads();
  s = ss[0] + ss[1] + ss[2] + ss[3];
  q = qq[0] + qq[1] + qq[2] + qq[3];
  const float mean = s * (1.0f / 1024.0f);
  const float var = q * (1.0f / 1024.0f) - mean * mean;
  const float rstd = rsqrtf(var + 1e-5f);
  f32x4 g4 = *(const f32x4*)(gw + threadIdx.x * 4);
  f32x4 b4 = *(const f32x4*)(bw + threadIdx.x * 4);
  f32x4 o;
#pragma unroll
  for (int j = 0; j < 4; ++j) o[j] = (v[j] - mean) * rstd * g4[j] + b4[j];
  store4(out + row * 1024 + threadIdx.x * 4, o);
}

// ---------------- time-shift mix -> bf16 ----------------
template <typename TIN>
__global__ __launch_bounds__(256) void mix_kernel(const TIN* __restrict__ x,
    const float* __restrict__ tm, const float* __restrict__ cm,
    __bf16* __restrict__ out) {
  const int idx = blockIdx.x * 256 + threadIdx.x;   // over B*T*C/4
  const int t = (idx >> 8) & 2047;                   // T=2048
  const int c = (idx & 255) * 4;                     // C/4=256
  const size_t base = ((size_t)(idx >> 8) << 10) + c;
  f32x4 xv = load4(x + base);
  f32x4 xm1 = {0.f, 0.f, 0.f, 0.f}, xp1 = {0.f, 0.f, 0.f, 0.f};
  if (t > 0)    xm1 = load4(x + base - 1024);
  if (t < 2047) xp1 = load4(x + base + 1024);
  f32x4 tm4 = *(const f32x4*)(tm + c);
  f32x4 cm4 = *(const f32x4*)(cm + c);
  f32x4 xc = (c < 512) ? xm1 : xp1;
  f32x4 o;
#pragma unroll
  for (int j = 0; j < 4; ++j)
    o[j] = xv[j] * tm4[j] + xm1[j] * (1.0f - tm4[j]) + xc[j] * cm4[j];
  store4(out + base, o);
}

// ---------------- WKV chunk-parallel scan (exact regroup of reference) ----------------
__global__ __launch_bounds__(256) void wkv_part(const __bf16* __restrict__ k,
    const __bf16* __restrict__ v, const float* __restrict__ td,
    float* __restrict__ scA, float* __restrict__ scB) {
  const int gid = blockIdx.x * 256 + threadIdx.x;   // b*32768 + j*1024 + c
  const int c = gid & 1023;
  const int j = (gid >> 10) & 31;
  const int b = gid >> 15;
  const float ed = expf(-expf(td[c]));
  float A = 0.f, Bv = 0.f;
  size_t off = ((size_t)(b * 2048 + j * 64) << 10) + c;
#pragma unroll 4
  for (int i = 0; i < 64; ++i, off += 1024) {
    const float kt = (float)k[off];
    const float kv = kt * (float)v[off];
    A = ed * A + kv;
    Bv = ed * Bv + kt;
  }
  scA[gid] = A;
  scB[gid] = Bv;
}

__global__ __launch_bounds__(256) void wkv_scan(const float* __restrict__ td,
    float* __restrict__ scA, float* __restrict__ scB) {
  const int gid = blockIdx.x * 256 + threadIdx.x;   // 8192 = b*1024 + c
  const int c = gid & 1023;
  const int b = gid >> 10;
  const float edL = expf(-expf(td[c]) * 64.0f);     // ed^64
  float a = 0.f, bb = 0.f;
  size_t off = ((size_t)b << 15) + c;
  for (int j = 0; j < 32; ++j, off += 1024) {
    const float Aj = scA[off], Bj = scB[off];
    scA[off] = a;            // carry INTO chunk j
    scB[off] = bb;
    a = edL * a + Aj;
    bb = edL * bb + Bj;
  }
}

__global__ __launch_bounds__(256) void wkv_apply(const __bf16* __restrict__ k,
    const __bf16* __restrict__ v, const __bf16* __restrict__ sr,
    const float* __restrict__ td, const float* __restrict__ tf,
    const float* __restrict__ scA, const float* __restrict__ scB,
    __bf16* __restrict__ srw) {
  const int gid = blockIdx.x * 256 + threadIdx.x;
  const int c = gid & 1023;
  const int j = (gid >> 10) & 31;
  const int b = gid >> 15;
  const float ed = expf(-expf(td[c]));
  const float eu = expf(tf[c]);
  float a = scA[gid], bb = scB[gid];
  size_t off = ((size_t)(b * 2048 + j * 64) << 10) + c;
#pragma unroll 4
  for (int i = 0; i < 64; ++i, off += 1024) {
    const float kt = (float)k[off];
    const float vt = (float)v[off];
    const float kv = kt * vt;
    const float y = (a + eu * kv) / (bb + eu * kt);
    srw[off] = (__bf16)((float)sr[off] * y);
    a = ed * a + kv;
    bb = ed * bb + kt;
  }
}

// ---------------- 256x256 deep-pipelined bf16 GEMM: out[m,n] = sum_k A[m,k]*W[n,k] ----
// 8 waves (2Mx4N), BK=32, ring-4 LDS buffers (128 KiB), counted vmcnt(8) pipeline
// (prefetch distance 3 K-tiles), T2 chunk swizzle (pre-swizzled global source +
// swizzled ds_read, LDS linear for global_load_lds), setprio around MFMA clusters.
enum { EPI_NONE = 0, EPI_EXP, EPI_SIG, EPI_RELU2, EPI_RESID, EPI_FINAL, EPI_KVR };

#define SBAR() { __builtin_amdgcn_s_barrier(); __builtin_amdgcn_sched_barrier(0); }
#define WAITL0() { asm volatile("s_waitcnt lgkmcnt(0)" ::: "memory"); __builtin_amdgcn_sched_barrier(0); }

template <int EPI>
__global__ __launch_bounds__(512, 2) void gemm256(
    const __bf16* __restrict__ A, const __bf16* __restrict__ W,
    void* outp, const void* res, const void* sig, const int N, const int K) {
  __shared__ __bf16 sA[4][8192];   // ring of 4 K-tile buffers, 256 rows x 32 cols
  __shared__ __bf16 sB[4][8192];
  const int tid = threadIdx.x;
  const int w = tid >> 6, l = tid & 63;
  const int wm = w >> 2, wn = w & 3;

  // bijective XCD swizzle (all grids have nwg % 8 == 0)
  const int nwg = gridDim.x * gridDim.y;
  int wg = blockIdx.y * gridDim.x + blockIdx.x;
  wg = (wg & 7) * (nwg >> 3) + (wg >> 3);
  const int m0 = (wg / gridDim.x) << 8;
  const int n0 = (wg % gridDim.x) << 8;

  // ---- staging: 2 chunks (16B) per matrix per thread per K-tile ----
  // LDS slot s=(i*8+w)*64+l -> row=s>>2, chunk c=l&3; global source chunk is
  // c ^ f(row), f(row)=(row&3)^((row>>2)&3) -> lane-only: (l&3)^((l>>2)&3)^(l>>4)
  const int cswz = (l & 3) ^ ((l >> 2) & 3) ^ (l >> 4);
  const int rst = w * 16 + (l >> 2);           // staging row for half 0
  const size_t dA0 = (size_t)(m0 + rst) * K + cswz * 8;
  const size_t dA1 = dA0 + (size_t)128 * K;
  const size_t dB0 = (size_t)(n0 + rst) * K + cswz * 8;
  const size_t dB1 = dB0 + (size_t)128 * K;
  const int NT = K >> 5;

  auto stA = [&](int t) {
    const int s = t & 3;
    const size_t ko = (size_t)t << 5;
    glds16(A + dA0 + ko, &sA[s][w * 512]);
    glds16(A + dA1 + ko, &sA[s][(8 + w) * 512]);
  };
  auto stB = [&](int t) {
    const int s = t & 3;
    const size_t ko = (size_t)t << 5;
    glds16(W + dB0 + ko, &sB[s][w * 512]);
    glds16(W + dB1 + ko, &sB[s][(8 + w) * 512]);
  };

  // ---- fragment read offsets (swizzled chunk within row) ----
  const int fl = (l & 3) ^ ((l >> 2) & 3);
  const int coff = ((l >> 4) ^ fl) << 3;       // element offset of 16B chunk
  const int aoff = ((wm << 7) + (l & 15)) * 32 + coff;
  const int boff = ((wn << 6) + (l & 15)) * 32 + coff;

  f32x4 acc[8][4] = {};

  // prologue: stage tiles 0,1,2 (12 loads); wait tile0 (leave 8 in flight)
  stA(0); stB(0); stA(1); stB(1); stA(2); stB(2);
  asm volatile("s_waitcnt vmcnt(8)" ::: "memory");
  __builtin_amdgcn_sched_barrier(0);
  SBAR();

  for (int kt = 0; kt < NT; ++kt) {
    const int slot = kt & 3;
    const __bf16* pa = &sA[slot][aoff];
    const __bf16* pb = &sB[slot][boff];
    bf16x8 bfr[4], afr[4];
    // ---- phase 0: B-frags + A-frags mi 0-3; stage A of tile kt+3 ----
#pragma unroll
    for (int i = 0; i < 4; ++i) bfr[i] = *(const bf16x8*)(pb + i * 512);
#pragma unroll
    for (int i = 0; i < 4; ++i) afr[i] = *(const bf16x8*)(pa + i * 512);
    if (kt + 3 < NT) stA(kt + 3);
    __builtin_amdgcn_sched_barrier(0);
    SBAR();
    WAITL0();
    __builtin_amdgcn_s_setprio(1);
#pragma unroll
    for (int mi = 0; mi < 4; ++mi)
#pragma unroll
      for (int ni = 0; ni < 4; ++ni)
        acc[mi][ni] = __builtin_amdgcn_mfma_f32_16x16x32_bf16(afr[mi], bfr[ni], acc[mi][ni], 0, 0, 0);
    __builtin_amdgcn_s_setprio(0);
    __builtin_amdgcn_sched_barrier(0);
    SBAR();
    // ---- phase 1: A-frags mi 4-7; stage B of tile kt+3 ----
#pragma unroll
    for (int i = 0; i < 4; ++i) afr[i] = *(const bf16x8*)(pa + (4 + i) * 512);
    if (kt + 3 < NT) stB(kt + 3);
    __builtin_amdgcn_sched_barrier(0);
    SBAR();
    WAITL0();
    __builtin_amdgcn_s_setprio(1);
#pragma unroll
    for (int mi = 0; mi < 4; ++mi)
#pragma unroll
      for (int ni = 0; ni < 4; ++ni)
        acc[4 + mi][ni] = __builtin_amdgcn_mfma_f32_16x16x32_bf16(afr[mi], bfr[ni], acc[4 + mi][ni], 0, 0, 0);
    __builtin_amdgcn_s_setprio(0);
    // ---- end of tile: counted drain (tail ramps 8 -> 4 -> 0) ----
    const int rem = NT - 2 - kt;
    if (rem >= 2)      { asm volatile("s_waitcnt vmcnt(8)" ::: "memory"); }
    else if (rem == 1) { asm volatile("s_waitcnt vmcnt(4)" ::: "memory"); }
    else               { asm volatile("s_waitcnt vmcnt(0)" ::: "memory"); }
    __builtin_amdgcn_sched_barrier(0);
    SBAR();
  }

  // ---- epilogue: C/D map col=lane&15, row=(lane>>4)*4+reg ----
  const int rl = (l >> 4) << 2, cl = l & 15;
#pragma unroll
  for (int mi = 0; mi < 8; ++mi) {
#pragma unroll
    for (int ni = 0; ni < 4; ++ni) {
#pragma unroll
      for (int e = 0; e < 4; ++e) {
        const int r = m0 + (wm << 7) + mi * 16 + rl + e;
        const int cidx = n0 + (wn << 6) + ni * 16 + cl;
        const size_t idx = (size_t)r * N + cidx;
        const float vacc = acc[mi][ni][e];
        if constexpr (EPI == EPI_NONE) {
          ((__bf16*)outp)[idx] = (__bf16)vacc;
        } else if constexpr (EPI == EPI_EXP) {
          ((__bf16*)outp)[idx] = (__bf16)expf(fminf(vacc, 60.0f));
        } else if constexpr (EPI == EPI_SIG) {
          ((__bf16*)outp)[idx] = (__bf16)(1.0f / (1.0f + expf(-vacc)));
        } else if constexpr (EPI == EPI_RELU2) {
          const float rv = fmaxf(vacc, 0.0f);
          ((__bf16*)outp)[idx] = (__bf16)(rv * rv);
        } else if constexpr (EPI == EPI_RESID) {
          ((__bf16*)outp)[idx] = (__bf16)(vacc + (float)((const __bf16*)res)[idx]);
        } else if constexpr (EPI == EPI_FINAL) {
          ((float*)outp)[idx] = ((const float*)res)[idx] + (float)((const __bf16*)sig)[idx] * vacc;
        } else {  // EPI_KVR: col block 0 -> k=exp(clamp), 1 -> v, 2 -> sigmoid(r)
          const int sel = cidx >> 10;               // wave-uniform (16-aligned blocks)
          const size_t oidx = (size_t)r * 1024 + (cidx & 1023);
          if (sel == 0)      ((__bf16*)outp)[oidx] = (__bf16)expf(fminf(vacc, 60.0f));
          else if (sel == 1) ((__bf16*)const_cast<void*>(res))[oidx] = (__bf16)vacc;
          else               ((__bf16*)const_cast<void*>(sig))[oidx] = (__bf16)(1.0f / (1.0f + expf(-vacc)));
        }
      }
    }
  }
}

// ---------------- launch ----------------
extern "C" void kernel_launch(void* const* d_in, const int* in_sizes, int n_in,
                              void* d_out, int out_size, void* d_ws, size_t ws_size,
                              hipStream_t stream) {
  (void)in_sizes; (void)n_in; (void)out_size;
  const float* x    = (const float*)d_in[0];
  const float* ln1g = (const float*)d_in[1];
  const float* ln1b = (const float*)d_in[2];
  const float* ln2g = (const float*)d_in[3];
  const float* ln2b = (const float*)d_in[4];
  const float* atm  = (const float*)d_in[5];
  const float* acm  = (const float*)d_in[6];
  const float* td   = (const float*)d_in[7];
  const float* tf   = (const float*)d_in[8];
  const float* Wk   = (const float*)d_in[9];
  const float* Wv   = (const float*)d_in[10];
  const float* Wr   = (const float*)d_in[11];
  const float* Wo   = (const float*)d_in[12];
  const float* ftm  = (const float*)d_in[13];
  const float* fcm  = (const float*)d_in[14];
  const float* Fk   = (const float*)d_in[15];
  const float* Fv   = (const float*)d_in[16];
  const float* Fr   = (const float*)d_in[17];

  constexpr size_t C = 1024, T = 2048, Bs = 8, H = 4096;
  constexpr size_t NT = Bs * T;        // 16384 tokens
  constexpr size_t NTC = NT * C;       // 16M elems
  constexpr size_t CC = C * C;
  constexpr size_t CH = C * H;

  // ---- workspace layout ----
  char* p = (char*)d_ws;
  auto takeb = [&](size_t elems) { __bf16* q = (__bf16*)p; p += elems * 2; return q; };
  __bf16* wKVR = takeb(3 * CC);   // [Wk; Wv; Wr] rows stacked -> (3072, 1024)
  __bf16* wWo  = takeb(CC);
  __bf16* wFk  = takeb(CH);
  __bf16* wFv  = takeb(CH);
  __bf16* wFr  = takeb(CC);
  __bf16* Ab   = takeb(NTC);      // x1 -> x2 (in-place residual)
  __bf16* Bb   = takeb(NTC);      // xm -> srw -> sr2
  __bf16* Db   = takeb(NTC);      // v  -> xm2
  float* scA = (float*)p; p += Bs * 32 * C * 4;   // wkv carries (b,j,c)
  float* scB = (float*)p; p += Bs * 32 * C * 4;
  __bf16* kk = (__bf16*)p;        // k lives here too (dead before Fk writes kk)
  const size_t used = (size_t)(p - (char*)d_ws);
  const size_t kkcap = ws_size > used ? ws_size - used : 0;
  int chunks = 4;                                   // 32 MiB kk  (round-2-proven floor)
  if (kkcap >= NT * H * 2)          chunks = 1;     // 128 MiB kk
  else if (kkcap >= NT * H)         chunks = 2;     // 64 MiB kk
  __bf16* Cb = kk;                 // k buffer (32 MiB) aliases kk region
  __bf16* sr  = (__bf16*)d_out;    // sigmoid(r) borrows d_out until ln2 overwrites it
  float*  x3  = (float*)d_out;

  auto cvt = [&](const float* src, size_t n, __bf16* dst) {
    const int n4 = (int)(n / 4);
    cvt_bf16<<<dim3((n4 + 255) / 256), dim3(256), 0, stream>>>(src, dst, n4);
  };
  cvt(Wk, CC, wKVR); cvt(Wv, CC, wKVR + CC); cvt(Wr, CC, wKVR + 2 * CC);
  cvt(Wo, CC, wWo); cvt(Fk, CH, wFk); cvt(Fv, CH, wFv); cvt(Fr, CC, wFr);

  const dim3 blk(256), blkG(512);

  // x1 = ln1(x)            [Ab]
  ln_kernel<float, __bf16><<<dim3((unsigned)NT), blk, 0, stream>>>(x, ln1g, ln1b, Ab);
  // xm = mix(x1)           [Bb]
  mix_kernel<__bf16><<<dim3((unsigned)(NTC / 1024)), blk, 0, stream>>>(Ab, atm, acm, Bb);
  // fused: k=exp(min(.,60)) [Cb], v [Db], sigmoid(r) [sr]
  gemm256<EPI_KVR><<<dim3(12, 64), blkG, 0, stream>>>(Bb, wKVR, Cb, Db, sr, 3072, 1024);
  // wkv: chunk partials -> carry scan -> apply (srw = sigmoid(r)*y into Bb)
  wkv_part<<<dim3(1024), blk, 0, stream>>>(Cb, Db, td, scA, scB);
  wkv_scan<<<dim3(32), blk, 0, stream>>>(td, scA, scB);
  wkv_apply<<<dim3(1024), blk, 0, stream>>>(Cb, Db, sr, td, tf, scA, scB, Bb);
  // x2 = x1 + srw@Wo^T     [Ab in-place]
  gemm256<EPI_RESID><<<dim3(4, 64), blkG, 0, stream>>>(Bb, wWo, Ab, Ab, nullptr, 1024, 1024);
  // x3 = ln2(x2)           [d_out, fp32]
  ln_kernel<__bf16, float><<<dim3((unsigned)NT), blk, 0, stream>>>(Ab, ln2g, ln2b, x3);
  // xm2 = mix(x3)          [Db]
  mix_kernel<float><<<dim3((unsigned)(NTC / 1024)), blk, 0, stream>>>(x3, ftm, fcm, Db);
  // sr2 = sigmoid(xm2@Fr^T) [Bb]
  gemm256<EPI_SIG><<<dim3(4, 64), blkG, 0, stream>>>(Db, wFr, Bb, nullptr, nullptr, 1024, 1024);
  // FFN: kk = relu(xm2@Fk^T)^2 [kk], out = x3 + sr2 * (kk@Fv^T)  (chunked if ws small)
  const size_t Mc = NT / chunks;
  for (int ch = 0; ch < chunks; ++ch) {
    const size_t ro = (size_t)ch * Mc;
    gemm256<EPI_RELU2><<<dim3(16, (unsigned)(Mc / 256)), blkG, 0, stream>>>(
        Db + ro * C, wFk, kk, nullptr, nullptr, 4096, 1024);
    gemm256<EPI_FINAL><<<dim3(4, (unsigned)(Mc / 256)), blkG, 0, stream>>>(
        kk, wFv, (float*)d_out + ro * C, (const float*)d_out + ro * C,
        Bb + ro * C, 1024, 4096);
  }
}

// Round 5
// 711.146 us; speedup vs baseline: 1.7855x; 1.1015x over previous
//
#include <hip/hip_runtime.h>
#include <hip/hip_bf16.h>

typedef float f32x4 __attribute__((ext_vector_type(4)));
typedef __bf16 bf16x8 __attribute__((ext_vector_type(8)));
typedef __bf16 bf16x4 __attribute__((ext_vector_type(4)));

#define DEVI static __device__ __forceinline__

DEVI void glds16(const void* g, void* l) {
  __builtin_amdgcn_global_load_lds((__attribute__((address_space(1))) void*)g,
                                   (__attribute__((address_space(3))) void*)l, 16, 0, 0);
}

DEVI f32x4 load4(const float* p) { return *(const f32x4*)p; }
DEVI f32x4 load4(const __bf16* p) {
  bf16x4 v = *(const bf16x4*)p;
  f32x4 o = { (float)v[0], (float)v[1], (float)v[2], (float)v[3] };
  return o;
}
DEVI void store4(float* p, f32x4 v) { *(f32x4*)p = v; }
DEVI void store4(__bf16* p, f32x4 v) {
  bf16x4 o = { (__bf16)v[0], (__bf16)v[1], (__bf16)v[2], (__bf16)v[3] };
  *(bf16x4*)p = o;
}

// ---------------- weight fp32 -> bf16 ----------------
__global__ void cvt_bf16(const float* __restrict__ in, __bf16* __restrict__ out, int n4) {
  int i = blockIdx.x * 256 + threadIdx.x;
  if (i < n4) {
    f32x4 v = *(const f32x4*)(in + (size_t)i * 4);
    store4(out + (size_t)i * 4, v);
  }
}

// ---------------- LayerNorm over C=1024, one block per token ----------------
template <typename TIN, typename TOUT>
__global__ __launch_bounds__(256) void ln_kernel(const TIN* __restrict__ x,
    const float* __restrict__ gw, const float* __restrict__ bw,
    TOUT* __restrict__ out) {
  const size_t row = blockIdx.x;
  f32x4 v = load4(x + row * 1024 + threadIdx.x * 4);
  float s = v[0] + v[1] + v[2] + v[3];
  float q = v[0]*v[0] + v[1]*v[1] + v[2]*v[2] + v[3]*v[3];
#pragma unroll
  for (int o = 32; o > 0; o >>= 1) { s += __shfl_down(s, o); q += __shfl_down(q, o); }
  __shared__ float ss[4], qq[4];
  const int w = threadIdx.x >> 6, l = threadIdx.x & 63;
  if (l == 0) { ss[w] = s; qq[w] = q; }
  __syncthreads();
  s = ss[0] + ss[1] + ss[2] + ss[3];
  q = qq[0] + qq[1] + qq[2] + qq[3];
  const float mean = s * (1.0f / 1024.0f);
  const float var = q * (1.0f / 1024.0f) - mean * mean;
  const float rstd = rsqrtf(var + 1e-5f);
  f32x4 g4 = *(const f32x4*)(gw + threadIdx.x * 4);
  f32x4 b4 = *(const f32x4*)(bw + threadIdx.x * 4);
  f32x4 o;
#pragma unroll
  for (int j = 0; j < 4; ++j) o[j] = (v[j] - mean) * rstd * g4[j] + b4[j];
  store4(out + row * 1024 + threadIdx.x * 4, o);
}

// ---------------- time-shift mix -> bf16 ----------------
template <typename TIN>
__global__ __launch_bounds__(256) void mix_kernel(const TIN* __restrict__ x,
    const float* __restrict__ tm, const float* __restrict__ cm,
    __bf16* __restrict__ out) {
  const int idx = blockIdx.x * 256 + threadIdx.x;   // over B*T*C/4
  const int t = (idx >> 8) & 2047;                   // T=2048
  const int c = (idx & 255) * 4;                     // C/4=256
  const size_t base = ((size_t)(idx >> 8) << 10) + c;
  f32x4 xv = load4(x + base);
  f32x4 xm1 = {0.f, 0.f, 0.f, 0.f}, xp1 = {0.f, 0.f, 0.f, 0.f};
  if (t > 0)    xm1 = load4(x + base - 1024);
  if (t < 2047) xp1 = load4(x + base + 1024);
  f32x4 tm4 = *(const f32x4*)(tm + c);
  f32x4 cm4 = *(const f32x4*)(cm + c);
  f32x4 xc = (c < 512) ? xm1 : xp1;
  f32x4 o;
#pragma unroll
  for (int j = 0; j < 4; ++j)
    o[j] = xv[j] * tm4[j] + xm1[j] * (1.0f - tm4[j]) + xc[j] * cm4[j];
  store4(out + base, o);
}

// ---------------- WKV chunk-parallel scan (exact regroup of reference) ----------------
__global__ __launch_bounds__(256) void wkv_part(const __bf16* __restrict__ k,
    const __bf16* __restrict__ v, const float* __restrict__ td,
    float* __restrict__ scA, float* __restrict__ scB) {
  const int gid = blockIdx.x * 256 + threadIdx.x;   // b*32768 + j*1024 + c
  const int c = gid & 1023;
  const int j = (gid >> 10) & 31;
  const int b = gid >> 15;
  const float ed = expf(-expf(td[c]));
  float A = 0.f, Bv = 0.f;
  size_t off = ((size_t)(b * 2048 + j * 64) << 10) + c;
#pragma unroll 4
  for (int i = 0; i < 64; ++i, off += 1024) {
    const float kt = (float)k[off];
    const float kv = kt * (float)v[off];
    A = ed * A + kv;
    Bv = ed * Bv + kt;
  }
  scA[gid] = A;
  scB[gid] = Bv;
}

__global__ __launch_bounds__(256) void wkv_scan(const float* __restrict__ td,
    float* __restrict__ scA, float* __restrict__ scB) {
  const int gid = blockIdx.x * 256 + threadIdx.x;   // 8192 = b*1024 + c
  const int c = gid & 1023;
  const int b = gid >> 10;
  const float edL = expf(-expf(td[c]) * 64.0f);     // ed^64
  float a = 0.f, bb = 0.f;
  size_t off = ((size_t)b << 15) + c;
  for (int j = 0; j < 32; ++j, off += 1024) {
    const float Aj = scA[off], Bj = scB[off];
    scA[off] = a;            // carry INTO chunk j
    scB[off] = bb;
    a = edL * a + Aj;
    bb = edL * bb + Bj;
  }
}

__global__ __launch_bounds__(256) void wkv_apply(const __bf16* __restrict__ k,
    const __bf16* __restrict__ v, const __bf16* __restrict__ sr,
    const float* __restrict__ td, const float* __restrict__ tf,
    const float* __restrict__ scA, const float* __restrict__ scB,
    __bf16* __restrict__ srw) {
  const int gid = blockIdx.x * 256 + threadIdx.x;
  const int c = gid & 1023;
  const int j = (gid >> 10) & 31;
  const int b = gid >> 15;
  const float ed = expf(-expf(td[c]));
  const float eu = expf(tf[c]);
  float a = scA[gid], bb = scB[gid];
  size_t off = ((size_t)(b * 2048 + j * 64) << 10) + c;
#pragma unroll 4
  for (int i = 0; i < 64; ++i, off += 1024) {
    const float kt = (float)k[off];
    const float vt = (float)v[off];
    const float kv = kt * vt;
    const float y = (a + eu * kv) / (bb + eu * kt);
    srw[off] = (__bf16)((float)sr[off] * y);
    a = ed * a + kv;
    bb = ed * bb + kt;
  }
}

// ---------------- 256x256 4-phase deep-pipelined bf16 GEMM ----------------
// out[m,n] = sum_k A[m,k]*W[n,k].  8 waves (2Mx4N), BK=64, dbuf LDS (128 KiB),
// 1 barrier/phase, counted vmcnt(4) (never 0 in steady state), G4 row-XOR
// swizzle both-sides (pre-swizzled global source + swizzled ds_read, LDS linear),
// setprio around 16-MFMA clusters, bijective XCD swizzle.
enum { EPI_NONE = 0, EPI_EXP, EPI_SIG, EPI_RELU2, EPI_RESID, EPI_FINAL, EPI_KVR };

#define SBAR() { __builtin_amdgcn_s_barrier(); __builtin_amdgcn_sched_barrier(0); }
#define WAITL0() { asm volatile("s_waitcnt lgkmcnt(0)" ::: "memory"); __builtin_amdgcn_sched_barrier(0); }
#define VMW(n) { asm volatile("s_waitcnt vmcnt(" #n ")" ::: "memory"); __builtin_amdgcn_sched_barrier(0); }

template <int EPI>
__global__ __launch_bounds__(512, 2) void gemm8p(
    const __bf16* __restrict__ A, const __bf16* __restrict__ W,
    void* outp, const void* res, const void* sig, const int N, const int K) {
  __shared__ __bf16 sA[2][16384];   // [buf][256 rows][64 cols], row = 128 B
  __shared__ __bf16 sB[2][16384];
  const int tid = threadIdx.x;
  const int w = tid >> 6, l = tid & 63;
  const int wm = w >> 2, wn = w & 3;

  // bijective XCD swizzle (all grids have nwg % 8 == 0)
  const int nwg = gridDim.x * gridDim.y;
  int wg = blockIdx.y * gridDim.x + blockIdx.x;
  wg = (wg & 7) * (nwg >> 3) + (wg >> 3);
  const int m0 = (wg / gridDim.x) << 8;
  const int n0 = (wg % gridDim.x) << 8;

  // ---- staging (global -> LDS, linear dest, pre-swizzled source) ----
  // lane l of each 1KB wave-issue: LDS row = base + (l>>3), chunk = l&7.
  // source chunk = (l&7) ^ (row&7) = (l&7) ^ (l>>3)   [bases are %8==0]
  const int lr = l >> 3;
  const int lc = (l & 7) ^ lr;
  const size_t gA = (size_t)(m0 + w * 8 + lr) * K + lc * 8;            // A issue i: +i*64 rows
  const size_t gB = (size_t)(n0 + wn * 64 + wm * 8 + lr) * K + lc * 8; // B issue j: +j*16 rows
  const int ldsA = w * 512;                  // (w*8 rows)*64
  const int ldsB = (wn * 64 + wm * 8) * 64;

  const int NTK = K >> 6;

#define STAGE_A(buf, kt, i) glds16(A + gA + (size_t)(i) * 64 * K + (size_t)(kt) * 64, &sA[buf][ldsA + (i) * 4096])
#define STAGE_B(buf, kt, j) glds16(W + gB + (size_t)(j) * 16 * K + (size_t)(kt) * 64, &sB[buf][ldsB + (j) * 1024])

  // ---- fragment reads (swizzled chunk) ----
  const int rA = (wm * 128 + (l & 15)) * 64;
  const int rB = (wn * 64 + (l & 15)) * 64;
  const int csw = l & 7;
  const int k0 = l >> 4;    // 0..3
#define LDA(buf, mi, kk) (*(const bf16x8*)&sA[buf][rA + (mi) * 1024 + ((((kk) * 4 + k0) ^ csw) << 3)])
#define LDB(buf, ni, kk) (*(const bf16x8*)&sB[buf][rB + (ni) * 1024 + ((((kk) * 4 + k0) ^ csw) << 3)])

  f32x4 acc[8][4] = {};
  bf16x8 afr[8], b0[4], b1[4];

  // prologue: stage tile 0 into buf 0, in consumption order
  STAGE_B(0, 0, 0); STAGE_B(0, 0, 1); STAGE_A(0, 0, 0); STAGE_A(0, 0, 2);
  STAGE_B(0, 0, 2); STAGE_B(0, 0, 3); STAGE_A(0, 0, 1); STAGE_A(0, 0, 3);

  for (int kt = 0; kt < NTK; ++kt) {
    const int buf = kt & 1, nb = buf ^ 1;
    const bool st = (kt + 1 < NTK);
    // ======== phase 0: Q(mi0-3, ni0-1) ========
    VMW(4); SBAR();
#pragma unroll
    for (int mi = 0; mi < 4; ++mi) {
      afr[mi * 2 + 0] = LDA(buf, mi, 0);
      afr[mi * 2 + 1] = LDA(buf, mi, 1);
    }
#pragma unroll
    for (int ni = 0; ni < 2; ++ni) {
      b0[ni * 2 + 0] = LDB(buf, ni, 0);
      b0[ni * 2 + 1] = LDB(buf, ni, 1);
    }
    if (st) { STAGE_B(nb, kt + 1, 0); STAGE_B(nb, kt + 1, 1); }
    WAITL0();
    __builtin_amdgcn_s_setprio(1);
#pragma unroll
    for (int mi = 0; mi < 4; ++mi)
#pragma unroll
      for (int ni = 0; ni < 2; ++ni)
#pragma unroll
        for (int kk = 0; kk < 2; ++kk)
          acc[mi][ni] = __builtin_amdgcn_mfma_f32_16x16x32_bf16(afr[mi*2+kk], b0[ni*2+kk], acc[mi][ni], 0, 0, 0);
    __builtin_amdgcn_s_setprio(0);
    // ======== phase 1: Q(mi0-3, ni2-3) ========
    if (st) { VMW(4); } else { VMW(2); }
    SBAR();
#pragma unroll
    for (int ni = 0; ni < 2; ++ni) {
      b1[ni * 2 + 0] = LDB(buf, ni + 2, 0);
      b1[ni * 2 + 1] = LDB(buf, ni + 2, 1);
    }
    if (st) { STAGE_A(nb, kt + 1, 0); STAGE_A(nb, kt + 1, 2); }
    WAITL0();
    __builtin_amdgcn_s_setprio(1);
#pragma unroll
    for (int mi = 0; mi < 4; ++mi)
#pragma unroll
      for (int ni = 0; ni < 2; ++ni)
#pragma unroll
        for (int kk = 0; kk < 2; ++kk)
          acc[mi][ni + 2] = __builtin_amdgcn_mfma_f32_16x16x32_bf16(afr[mi*2+kk], b1[ni*2+kk], acc[mi][ni + 2], 0, 0, 0);
    __builtin_amdgcn_s_setprio(0);
    // ======== phase 2: Q(mi4-7, ni0-1) ========
    if (st) { VMW(4); } else { VMW(0); }
    SBAR();
#pragma unroll
    for (int mi = 0; mi < 4; ++mi) {
      afr[mi * 2 + 0] = LDA(buf, mi + 4, 0);
      afr[mi * 2 + 1] = LDA(buf, mi + 4, 1);
    }
    if (st) { STAGE_B(nb, kt + 1, 2); STAGE_B(nb, kt + 1, 3); }
    WAITL0();
    __builtin_amdgcn_s_setprio(1);
#pragma unroll
    for (int mi = 0; mi < 4; ++mi)
#pragma unroll
      for (int ni = 0; ni < 2; ++ni)
#pragma unroll
        for (int kk = 0; kk < 2; ++kk)
          acc[mi + 4][ni] = __builtin_amdgcn_mfma_f32_16x16x32_bf16(afr[mi*2+kk], b0[ni*2+kk], acc[mi + 4][ni], 0, 0, 0);
    __builtin_amdgcn_s_setprio(0);
    // ======== phase 3: Q(mi4-7, ni2-3) ======== (no reads, no barrier)
    if (st) { STAGE_A(nb, kt + 1, 1); STAGE_A(nb, kt + 1, 3); }
    __builtin_amdgcn_s_setprio(1);
#pragma unroll
    for (int mi = 0; mi < 4; ++mi)
#pragma unroll
      for (int ni = 0; ni < 2; ++ni)
#pragma unroll
        for (int kk = 0; kk < 2; ++kk)
          acc[mi + 4][ni + 2] = __builtin_amdgcn_mfma_f32_16x16x32_bf16(afr[mi*2+kk], b1[ni*2+kk], acc[mi + 4][ni + 2], 0, 0, 0);
    __builtin_amdgcn_s_setprio(0);
  }

  // ---- epilogue: C/D map col=lane&15, row=(lane>>4)*4+reg ----
  const int rl = (l >> 4) << 2, cl = l & 15;
#pragma unroll
  for (int mi = 0; mi < 8; ++mi) {
#pragma unroll
    for (int ni = 0; ni < 4; ++ni) {
#pragma unroll
      for (int e = 0; e < 4; ++e) {
        const int r = m0 + (wm << 7) + mi * 16 + rl + e;
        const int cidx = n0 + (wn << 6) + ni * 16 + cl;
        const size_t idx = (size_t)r * N + cidx;
        const float vacc = acc[mi][ni][e];
        if constexpr (EPI == EPI_NONE) {
          ((__bf16*)outp)[idx] = (__bf16)vacc;
        } else if constexpr (EPI == EPI_EXP) {
          ((__bf16*)outp)[idx] = (__bf16)expf(fminf(vacc, 60.0f));
        } else if constexpr (EPI == EPI_SIG) {
          ((__bf16*)outp)[idx] = (__bf16)(1.0f / (1.0f + expf(-vacc)));
        } else if constexpr (EPI == EPI_RELU2) {
          const float rv = fmaxf(vacc, 0.0f);
          ((__bf16*)outp)[idx] = (__bf16)(rv * rv);
        } else if constexpr (EPI == EPI_RESID) {
          ((__bf16*)outp)[idx] = (__bf16)(vacc + (float)((const __bf16*)res)[idx]);
        } else if constexpr (EPI == EPI_FINAL) {
          ((float*)outp)[idx] = ((const float*)res)[idx] + (float)((const __bf16*)sig)[idx] * vacc;
        } else {  // EPI_KVR: col block 0 -> k=exp(clamp), 1 -> v, 2 -> sigmoid(r)
          const int sel = cidx >> 10;               // wave-uniform (16-aligned blocks)
          const size_t oidx = (size_t)r * 1024 + (cidx & 1023);
          if (sel == 0)      ((__bf16*)outp)[oidx] = (__bf16)expf(fminf(vacc, 60.0f));
          else if (sel == 1) ((__bf16*)const_cast<void*>(res))[oidx] = (__bf16)vacc;
          else               ((__bf16*)const_cast<void*>(sig))[oidx] = (__bf16)(1.0f / (1.0f + expf(-vacc)));
        }
      }
    }
  }
}

// ---------------- launch ----------------
extern "C" void kernel_launch(void* const* d_in, const int* in_sizes, int n_in,
                              void* d_out, int out_size, void* d_ws, size_t ws_size,
                              hipStream_t stream) {
  (void)in_sizes; (void)n_in; (void)out_size;
  const float* x    = (const float*)d_in[0];
  const float* ln1g = (const float*)d_in[1];
  const float* ln1b = (const float*)d_in[2];
  const float* ln2g = (const float*)d_in[3];
  const float* ln2b = (const float*)d_in[4];
  const float* atm  = (const float*)d_in[5];
  const float* acm  = (const float*)d_in[6];
  const float* td   = (const float*)d_in[7];
  const float* tf   = (const float*)d_in[8];
  const float* Wk   = (const float*)d_in[9];
  const float* Wv   = (const float*)d_in[10];
  const float* Wr   = (const float*)d_in[11];
  const float* Wo   = (const float*)d_in[12];
  const float* ftm  = (const float*)d_in[13];
  const float* fcm  = (const float*)d_in[14];
  const float* Fk   = (const float*)d_in[15];
  const float* Fv   = (const float*)d_in[16];
  const float* Fr   = (const float*)d_in[17];

  constexpr size_t C = 1024, T = 2048, Bs = 8, H = 4096;
  constexpr size_t NT = Bs * T;        // 16384 tokens
  constexpr size_t NTC = NT * C;       // 16M elems
  constexpr size_t CC = C * C;
  constexpr size_t CH = C * H;

  // ---- workspace layout ----
  char* p = (char*)d_ws;
  auto takeb = [&](size_t elems) { __bf16* q = (__bf16*)p; p += elems * 2; return q; };
  __bf16* wKVR = takeb(3 * CC);   // [Wk; Wv; Wr] rows stacked -> (3072, 1024)
  __bf16* wWo  = takeb(CC);
  __bf16* wFk  = takeb(CH);
  __bf16* wFv  = takeb(CH);
  __bf16* wFr  = takeb(CC);
  __bf16* Ab   = takeb(NTC);      // x1 -> x2 (in-place residual)
  __bf16* Bb   = takeb(NTC);      // xm -> srw -> sr2
  __bf16* Db   = takeb(NTC);      // v  -> xm2
  float* scA = (float*)p; p += Bs * 32 * C * 4;   // wkv carries (b,j,c)
  float* scB = (float*)p; p += Bs * 32 * C * 4;
  __bf16* kk = (__bf16*)p;        // k lives here too (dead before Fk writes kk)
  const size_t used = (size_t)(p - (char*)d_ws);
  const size_t kkcap = ws_size > used ? ws_size - used : 0;
  int chunks = 4;                                   // 32 MiB kk
  if (kkcap >= NT * H * 2)          chunks = 1;     // 128 MiB kk
  else if (kkcap >= NT * H)         chunks = 2;     // 64 MiB kk
  __bf16* Cb = kk;                 // k buffer (32 MiB) aliases kk region
  __bf16* sr  = (__bf16*)d_out;    // sigmoid(r) borrows d_out until ln2 overwrites it
  float*  x3  = (float*)d_out;

  auto cvt = [&](const float* src, size_t n, __bf16* dst) {
    const int n4 = (int)(n / 4);
    cvt_bf16<<<dim3((n4 + 255) / 256), dim3(256), 0, stream>>>(src, dst, n4);
  };
  cvt(Wk, CC, wKVR); cvt(Wv, CC, wKVR + CC); cvt(Wr, CC, wKVR + 2 * CC);
  cvt(Wo, CC, wWo); cvt(Fk, CH, wFk); cvt(Fv, CH, wFv); cvt(Fr, CC, wFr);

  const dim3 blk(256), blkG(512);

  // x1 = ln1(x)            [Ab]
  ln_kernel<float, __bf16><<<dim3((unsigned)NT), blk, 0, stream>>>(x, ln1g, ln1b, Ab);
  // xm = mix(x1)           [Bb]
  mix_kernel<__bf16><<<dim3((unsigned)(NTC / 1024)), blk, 0, stream>>>(Ab, atm, acm, Bb);
  // fused: k=exp(min(.,60)) [Cb], v [Db], sigmoid(r) [sr]
  gemm8p<EPI_KVR><<<dim3(12, 64), blkG, 0, stream>>>(Bb, wKVR, Cb, Db, sr, 3072, 1024);
  // wkv: chunk partials -> carry scan -> apply (srw = sigmoid(r)*y into Bb)
  wkv_part<<<dim3(1024), blk, 0, stream>>>(Cb, Db, td, scA, scB);
  wkv_scan<<<dim3(32), blk, 0, stream>>>(td, scA, scB);
  wkv_apply<<<dim3(1024), blk, 0, stream>>>(Cb, Db, sr, td, tf, scA, scB, Bb);
  // x2 = x1 + srw@Wo^T     [Ab in-place]
  gemm8p<EPI_RESID><<<dim3(4, 64), blkG, 0, stream>>>(Bb, wWo, Ab, Ab, nullptr, 1024, 1024);
  // x3 = ln2(x2)           [d_out, fp32]
  ln_kernel<__bf16, float><<<dim3((unsigned)NT), blk, 0, stream>>>(Ab, ln2g, ln2b, x3);
  // xm2 = mix(x3)          [Db]
  mix_kernel<float><<<dim3((unsigned)(NTC / 1024)), blk, 0, stream>>>(x3, ftm, fcm, Db);
  // sr2 = sigmoid(xm2@Fr^T) [Bb]
  gemm8p<EPI_SIG><<<dim3(4, 64), blkG, 0, stream>>>(Db, wFr, Bb, nullptr, nullptr, 1024, 1024);
  // FFN: kk = relu(xm2@Fk^T)^2 [kk], out = x3 + sr2 * (kk@Fv^T)  (chunked if ws small)
  const size_t Mc = NT / chunks;
  for (int ch = 0; ch < chunks; ++ch) {
    const size_t ro = (size_t)ch * Mc;
    gemm8p<EPI_RELU2><<<dim3(16, (unsigned)(Mc / 256)), blkG, 0, stream>>>(
        Db + ro * C, wFk, kk, nullptr, nullptr, 4096, 1024);
    gemm8p<EPI_FINAL><<<dim3(4, (unsigned)(Mc / 256)), blkG, 0, stream>>>(
        kk, wFv, (float*)d_out + ro * C, (const float*)d_out + ro * C,
        Bb + ro * C, 1024, 4096);
  }
}